// Round 4
// baseline (51.497 us; speedup 1.0000x reference)
//
#include <hip/hip_runtime.h>

#define NPROLIF 12
#define NLIN 18
#define ROW 22                      // floats per element row
#define BLK 256                     // threads per block
#define F4_PER_SLAB (BLK*ROW/4)     // 1408 float4 per slab
#define NSLAB 8192                  // B*T/BLK
#define GRID 768                    // 3 blocks/CU (LDS-bound)

#define AS1 __attribute__((address_space(1)))
#define AS3 __attribute__((address_space(3)))

// branchless 4-way select (wave-uniform index): 3 v_cndmask on the VALU pipe
__device__ __forceinline__ float sel4(unsigned i, float x0, float x1, float x2, float x3) {
    float lo = (i & 1u) ? x1 : x0;
    float hi = (i & 1u) ? x3 : x2;
    return (i & 2u) ? hi : lo;
}

__global__ __launch_bounds__(BLK) void sindy_kernel(
    const float* __restrict__ cand,
    const float* __restrict__ a,
    const float* __restrict__ ss,
    const float* __restrict__ sgn,
    const float* __restrict__ K1p,
    const float* __restrict__ thetap,
    const float* __restrict__ K2p,
    const int* __restrict__ pidx,
    const int* __restrict__ lidx,
    const int* __restrict__ sprop,
    float* __restrict__ out)
{
    __shared__ float sRow[2][BLK*ROW];  // 2 x 22528 B, linear (global_load_lds dest)
    __shared__ uint2 sPP[NPROLIF];
    __shared__ uint4 sLP[NLIN];
    __shared__ float sScal[4];          // K1, 1/theta, K2, coef0

    const int tid  = threadIdx.x;
    const int bid  = blockIdx.x;
    const int wave = tid >> 6;

    const int niter = (NSLAB - bid + GRID - 1) / GRID;   // 10 or 11, block-uniform

    // ---- const build FIRST (its loads drain before any DMA is issued) ----
    if (tid < NPROLIF) {
        int i = tid;
        int ia = pidx[i*3+0], ib = pidx[i*3+1], ic = pidx[i*3+2];
        float av = a[1+i];
        bool keep = sprop[1+i] ? (av >= 0.f) : (av <= 0.f);
        unsigned offs = (unsigned)ia | ((unsigned)ib << 2) | ((unsigned)(16 + ic*4) << 8);
        sPP[i] = make_uint2(offs, __float_as_uint(keep ? av : 0.f));
    } else if (tid < NPROLIF + NLIN) {           // tids 12..29
        int j = tid - NPROLIF;
        int i0 = lidx[j*2+0], i1 = lidx[j*2+1];
        float av = a[1+NPROLIF+j];
        bool keep = sprop[1+NPROLIF+j] ? (av >= 0.f) : (av <= 0.f);
        unsigned offs = (unsigned)i0 | ((unsigned)(16 + i1*4) << 8);
        sLP[j] = make_uint4(offs,
                            __float_as_uint(keep ? av : 0.f),
                            __float_as_uint(500.f * sgn[j]),
                            __float_as_uint(ss[i1]));
    } else if (tid == NPROLIF + NLIN) {          // tid 30
        float av = a[0];
        bool keep = sprop[0] ? (av >= 0.f) : (av <= 0.f);
        sScal[0] = K1p[0];
        sScal[1] = 1.0f / thetap[0];
        sScal[2] = K2p[0];
        sScal[3] = keep ? av : 0.f;
    }

    // ---- DMA staging: 7 wave-uniform issues per slab (5x16B + 2x4B tail) ----
    auto ISSUE = [&](int slab, int buf) {
        const float4* g4 = reinterpret_cast<const float4*>(cand)
                           + (long long)slab * F4_PER_SLAB;
        float4* s4 = reinterpret_cast<float4*>(&sRow[buf][0]);
        #pragma unroll
        for (int k = 0; k < 5; ++k) {
            __builtin_amdgcn_global_load_lds(
                (const AS1 void*)(g4 + k*BLK + tid),
                (AS3 void*)(s4 + k*BLK + (wave << 6)), 16, 0, 0);
        }
        // tail: 512 dwords = 2 passes of 256 threads x 4B
        const float* gf = (const float*)(g4 + 5*BLK);
        float* sf = (float*)(s4 + 5*BLK);
        __builtin_amdgcn_global_load_lds(
            (const AS1 void*)(gf + tid),
            (AS3 void*)(sf + (wave << 6)), 4, 0, 0);
        __builtin_amdgcn_global_load_lds(
            (const AS1 void*)(gf + 256 + tid),
            (AS3 void*)(sf + 256 + (wave << 6)), 4, 0, 0);
    };

    ISSUE(bid, 0);              // slab 0 -> buf0   (7 outstanding)
    ISSUE(bid + GRID, 1);       // slab 1 -> buf1   (14 outstanding; niter >= 10 always)

    asm volatile("s_waitcnt lgkmcnt(0)" ::: "memory");   // const ds_writes visible
    __builtin_amdgcn_s_barrier();

    const float K1 = sScal[0], invTh = sScal[1], K2 = sScal[2], coef0 = sScal[3];

    int buf = 0;
    for (int i = 0; i < niter; ++i) {
        // counted wait: keep next slab's 7 loads in flight; only drain fully at the end
        if (i + 1 < niter) { asm volatile("s_waitcnt vmcnt(7)" ::: "memory"); }
        else               { asm volatile("s_waitcnt vmcnt(0)" ::: "memory"); }
        __builtin_amdgcn_sched_barrier(0);
        __builtin_amdgcn_s_barrier();          // buf[i&1] fully staged for all waves

        const char* row = (const char*)&sRow[buf][tid*ROW];  // [con, x0,x1,x2, prot0..17]
        float con = sRow[buf][tid*ROW+0];
        float x0  = sRow[buf][tid*ROW+1];
        float x1  = sRow[buf][tid*ROW+2];
        float x2  = sRow[buf][tid*ROW+3];
        float xs  = x0 + x1 + x2;

        float acc = coef0 * con;

        #pragma unroll
        for (int t = 0; t < NPROLIF; ++t) {
            uint2 pp = sPP[t];
            float coef = __uint_as_float(pp.y);
            float pA = sel4(pp.x & 3u, x0, x1, x2, xs);
            float pB = sel4((pp.x >> 2) & 3u, x0, x1, x2, xs);
            float pC = *(const float*)(row + ((pp.x >> 8) & 0xffu));
            float h  = pC * __builtin_amdgcn_rcpf(K1 + pC);
            acc += coef * (pA * (1.0f - pB * invTh) * h);
        }

        #pragma unroll
        for (int t = 0; t < NLIN; ++t) {
            uint4 lp = sLP[t];
            float coef = __uint_as_float(lp.y);
            float A    = __uint_as_float(lp.z);          // 500*sign
            float ssv  = __uint_as_float(lp.w);
            float l0 = sel4(lp.x & 3u, x0, x1, x2, xs);
            float pr = *(const float*)(row + ((lp.x >> 8) & 0xffu));
            float dp  = pr - ssv;
            float adp = fabsf(dp);
            float h   = adp * __builtin_amdgcn_rcpf(K2 + adp);
            float z   = A * dp - 25.0f;                  // 500*(sign*dp - 0.05)
            float e   = __expf(-z);
            float sig = __builtin_amdgcn_rcpf(1.0f + e);
            acc += coef * (l0 * h * sig);
        }

        const int slab = bid + i * GRID;
        out[(long long)slab * BLK + tid] = acc;          // +1 vmcnt, folded into count

        __builtin_amdgcn_s_barrier();                    // all waves done reading buf
        if (i + 2 < niter) ISSUE(bid + (i + 2) * GRID, buf);   // overwrite is now safe
        buf ^= 1;
    }

    // steady-state vmcnt ledger per wave/iter at the wait point:
    //   outstanding = 7 (slab i+1) + 1 (store i-1) + 7 (slab i+2) = 15 -> wait(7)
    //   drains slab i+1's 7 + the old store, keeps the newest 7.  last iter: wait(0).
}

extern "C" void kernel_launch(void* const* d_in, const int* in_sizes, int n_in,
                              void* d_out, int out_size, void* d_ws, size_t ws_size,
                              hipStream_t stream) {
    const float* cand = (const float*)d_in[0];
    const float* a    = (const float*)d_in[1];
    const float* ss   = (const float*)d_in[2];
    const float* sgn  = (const float*)d_in[3];
    const float* K1   = (const float*)d_in[4];
    const float* th   = (const float*)d_in[5];
    const float* K2   = (const float*)d_in[6];
    const int*   pidx = (const int*)d_in[7];
    const int*   lidx = (const int*)d_in[8];
    const int*   sp   = (const int*)d_in[9];
    float* out = (float*)d_out;

    hipLaunchKernelGGL(sindy_kernel, dim3(GRID), dim3(BLK), 0, stream,
                       cand, a, ss, sgn, K1, th, K2, pidx, lidx, sp, out);
}